// Round 17
// baseline (89.909 us; speedup 1.0000x reference)
//
#include <hip/hip_runtime.h>
#include <hip/hip_bf16.h>
#include <hip/hip_fp8.h>

#define B_ 8192
#define C_ 10000
#define D_ 128
#define CPAD 10112      // 158 * 64
#define NPADC 112       // CPAD - C_
#define NT_TOT 158      // 64-col tiles
#define NSTRIP 16
#define STRIPW 10       // strips 0..14 -> 10 tiles, strip 15 -> 8
#define UPD_BLOCKS 2528 // CPAD/4
#define CVAL_BLOCKS 2048// B_/4
#define GEMM_BLOCKS 512 // 32 bm x 16 strips

typedef float f32x4 __attribute__((ext_vector_type(4)));
typedef int   i32x8 __attribute__((ext_vector_type(8)));

typedef const __attribute__((address_space(1))) uint32_t gu32;
typedef __attribute__((address_space(3))) uint32_t lu32;

// ---------------- ws layout (float offsets) ----------------
// counts    : [0, 10240)        (slot 10200 = done-counter, zeroed with counts)
// sumx      : [10240, 1290240)
// git_row   : [1290240, 1298432)
// xnorm     : [1298432, 1306624)
// cent_val  : [1306624, 1314816)
// cnorm     : [1314816, 1325056)   (CPAD, pad = 0)
// x_fp8     : byte 5,300,224  (8192 x 128 = 1 MB)
// c_fp8     : byte 7,397,376  (CPAD x 128, pad rows zero)

__global__ void zero_ws(float4* __restrict__ ws) {
    int idx = blockIdx.x * 256 + threadIdx.x;
    if (idx < 324608) ws[idx] = float4{0.f, 0.f, 0.f, 0.f};
}

// Fused: segment-sum atomics + fp8 cast + xnorm (single pass over x).
__global__ void scatter_prep(const float* __restrict__ x, const int* __restrict__ labels,
                             float* __restrict__ counts, float* __restrict__ sumx,
                             float* __restrict__ xnorm, unsigned char* __restrict__ xb8) {
    int tid = threadIdx.x;
    int w = tid >> 6, lane = tid & 63;
    int i = blockIdx.x * 4 + w;
    int l = labels[i];
    float2 v = *(const float2*)&x[i * D_ + lane * 2];
    atomicAdd(&sumx[l * D_ + lane * 2], v.x);
    atomicAdd(&sumx[l * D_ + lane * 2 + 1], v.y);
    if (lane == 0) atomicAdd(&counts[l], 1.0f);
    __hip_fp8_e4m3 a(v.x), b(v.y);
    unsigned short pk = (unsigned short)a.__x | ((unsigned short)b.__x << 8);
    *(unsigned short*)&xb8[i * D_ + lane * 2] = pk;
    float s = v.x * v.x + v.y * v.y;
    #pragma unroll
    for (int m = 1; m < 64; m <<= 1) s += __shfl_xor(s, m);
    if (lane == 0) xnorm[i] = s;
}

__global__ void upd_cvals(const float* __restrict__ centers, const float* __restrict__ counts,
                          const float* __restrict__ sumx, float* __restrict__ cnorm,
                          unsigned char* __restrict__ cb8, const float* __restrict__ lr,
                          const float* __restrict__ x, const int* __restrict__ labels,
                          float* __restrict__ cent_val) {
    int tid = threadIdx.x;
    int w = tid >> 6, lane = tid & 63;
    int bid = blockIdx.x;
    float lrv = lr[0];

    if (bid < UPD_BLOCKS) {
        int c = bid * 4 + w;
        if (c >= C_) {
            *(unsigned short*)&cb8[c * D_ + lane * 2] = 0;
            if (lane == 0) cnorm[c] = 0.0f;
            return;
        }
        float cnt = counts[c];
        float2 cv = *(const float2*)&centers[c * D_ + lane * 2];
        float2 sx = *(const float2*)&sumx[c * D_ + lane * 2];
        float inv = 1.0f / (1.0f + cnt);
        float nx = cv.x - lrv * (cnt * cv.x - sx.x) * inv;
        float ny = cv.y - lrv * (cnt * cv.y - sx.y) * inv;
        __hip_fp8_e4m3 a(nx), b(ny);
        unsigned short pk = (unsigned short)a.__x | ((unsigned short)b.__x << 8);
        *(unsigned short*)&cb8[c * D_ + lane * 2] = pk;
        float s = nx * nx + ny * ny;
        #pragma unroll
        for (int m = 1; m < 64; m <<= 1) s += __shfl_xor(s, m);
        if (lane == 0) cnorm[c] = s;
    } else {
        int i = (bid - UPD_BLOCKS) * 4 + w;
        int l = labels[i];
        float cnt = counts[l];
        float inv = 1.0f / (1.0f + cnt);
        float2 a  = *(const float2*)&x[i * D_ + lane * 2];
        float2 cv = *(const float2*)&centers[l * D_ + lane * 2];
        float2 sx = *(const float2*)&sumx[l * D_ + lane * 2];
        float nx = cv.x - lrv * (cnt * cv.x - sx.x) * inv;
        float ny = cv.y - lrv * (cnt * cv.y - sx.y) * inv;
        float dx = a.x - nx, dy = a.y - ny;
        float s = dx * dx + dy * dy;
        #pragma unroll
        for (int m = 1; m < 64; m <<= 1) s += __shfl_xor(s, m);
        if (lane == 0) cent_val[i] = s;
    }
}

// MX-FP8 GEMM + git (exact R15 core, no setprio) + one dedicated reducer
// block (bid==GEMM_BLOCKS) that spin-waits for all compute blocks and then
// performs the final reduction. Top-level branch keeps regalloc clean.
__global__ void __launch_bounds__(256, 2)
gemm_git(const unsigned char* __restrict__ xb8, const unsigned char* __restrict__ cb8,
         const float* __restrict__ xnorm, const float* __restrict__ cnorm,
         float* __restrict__ git_row, const float* __restrict__ cent_val,
         float* __restrict__ out, int* __restrict__ counter) {
    int tid = threadIdx.x;
    int bid = blockIdx.x;

    if (bid == GEMM_BLOCKS) {
        // ---- reducer block: wait for all compute blocks, then reduce ----
        if (tid == 0) {
            while (__hip_atomic_load(counter, __ATOMIC_ACQUIRE, __HIP_MEMORY_SCOPE_AGENT)
                   < GEMM_BLOCKS)
                __builtin_amdgcn_s_sleep(8);
        }
        __syncthreads();
        int w = tid >> 6, lane = tid & 63;
        float cl = 0.0f, gl = 0.0f;
        for (int i = tid; i < B_; i += 256) {
            float c = cent_val[i];
            cl += fminf(fmaxf(c, 1e-12f), 1e12f);
            float gr = __hip_atomic_load(&git_row[i], __ATOMIC_RELAXED, __HIP_MEMORY_SCOPE_AGENT);
            float g = gr - 1.0f / (1.0f + c) - (float)NPADC / (1.0f + xnorm[i]);
            gl += fminf(fmaxf(g, 1e-12f), 1e12f);
        }
        #pragma unroll
        for (int m = 1; m < 64; m <<= 1) { cl += __shfl_xor(cl, m); gl += __shfl_xor(gl, m); }
        __shared__ float red[8];
        if (lane == 0) { red[w] = cl; red[4 + w] = gl; }
        __syncthreads();
        if (tid == 0) {
            out[0] = (red[0] + red[1] + red[2] + red[3]) / (float)B_;
            out[1] = (red[4] + red[5] + red[6] + red[7]) / (float)B_;
        }
        return;
    }

    __shared__ char ldsB[3][8192];    // 64 B-rows x 128B fp8, XOR-swizzled chunks
    __shared__ float cnLDS[STRIPW * 64];

    int w = tid >> 6, lane = tid & 63;
    int lr_ = lane & 15, lg = lane >> 4;
    int bm = bid & 31;
    int strip = bid >> 5;             // 0..15
    int row0 = bm * 256 + w * 64;
    int bn0 = strip * STRIPW;
    int nt = (strip == NSTRIP - 1) ? (NT_TOT - bn0) : STRIPW;

    // A fragments: lane holds row (row0+f*16+lr_), k-bytes [lg*32, +32); pinned.
    i32x8 af[4];
    #pragma unroll
    for (int f = 0; f < 4; f++) {
        const uint4* pa = (const uint4*)(xb8 + (size_t)(row0 + f * 16 + lr_) * 128 + lg * 32);
        uint4 u0 = pa[0], u1 = pa[1];
        asm volatile("" : "+v"(u0.x), "+v"(u0.y), "+v"(u0.z), "+v"(u0.w),
                          "+v"(u1.x), "+v"(u1.y), "+v"(u1.z), "+v"(u1.w));
        af[f] = i32x8{(int)u0.x, (int)u0.y, (int)u0.z, (int)u0.w,
                      (int)u1.x, (int)u1.y, (int)u1.z, (int)u1.w};
    }

    float xn1[4][4];
    #pragma unroll
    for (int fm = 0; fm < 4; fm++)
        #pragma unroll
        for (int r = 0; r < 4; r++) {
            float v = 1.0f + xnorm[row0 + fm * 16 + lg * 4 + r];
            asm volatile("" : "+v"(v));
            xn1[fm][r] = v;
        }

    float gitsum[4][4] = {};

    // stage: tile = 64 rows x 128B = 512 16B-slots; 256 threads cover 2 each.
    const char* gB = (const char*)cb8;
    int sr0 = tid >> 3,          sc0 = (tid & 7) ^ (sr0 & 7);
    int sr1 = (tid + 256) >> 3,  sc1 = ((tid + 256) & 7) ^ (sr1 & 7);
    size_t goff0 = (size_t)sr0 * 128 + sc0 * 16;
    size_t goff1 = (size_t)sr1 * 128 + sc1 * 16;

    auto stage = [&](int t, int buf) {
        const char* base = gB + (size_t)(bn0 + t) * 64 * 128;   // tile = 64 x 128B
        __builtin_amdgcn_global_load_lds((gu32*)(base + goff0),
                                         (lu32*)&ldsB[buf][tid * 16], 16, 0, 0);
        __builtin_amdgcn_global_load_lds((gu32*)(base + goff1),
                                         (lu32*)&ldsB[buf][4096 + tid * 16], 16, 0, 0);
    };

    // prologue: cnorm -> LDS, stage tiles 0 and 1; single full drain.
    for (int i = tid; i < nt * 64; i += 256) cnLDS[i] = cnorm[bn0 * 64 + i];
    stage(0, 0);
    if (nt > 1) stage(1, 1);
    __syncthreads();

    for (int t = 0; t < nt; ++t) {
        int bc = t % 3;
        if (t + 2 < nt) stage(t + 2, (t + 2) % 3);

        if (t + 2 < nt)      asm volatile("s_waitcnt vmcnt(4)" ::: "memory");
        else if (t + 1 < nt) asm volatile("s_waitcnt vmcnt(2)" ::: "memory");
        else                 asm volatile("s_waitcnt vmcnt(0)" ::: "memory");
        __builtin_amdgcn_sched_barrier(0);
        __builtin_amdgcn_s_barrier();
        __builtin_amdgcn_sched_barrier(0);

        float cn[4];
        #pragma unroll
        for (int fn = 0; fn < 4; fn++) cn[fn] = cnLDS[t * 64 + fn * 16 + lr_];

        // B fragments: col-row = fn*16+lr_, k-bytes [lg*32, +32) (2 chunks).
        i32x8 bfk[4];
        int r7 = lr_ & 7;
        #pragma unroll
        for (int fn = 0; fn < 4; fn++) {
            const char* rowp = &ldsB[bc][(fn * 16 + lr_) * 128];
            uint4 q0 = *(const uint4*)(rowp + (((lg * 2)     ^ r7) * 16));
            uint4 q1 = *(const uint4*)(rowp + (((lg * 2 + 1) ^ r7) * 16));
            bfk[fn] = i32x8{(int)q0.x, (int)q0.y, (int)q0.z, (int)q0.w,
                            (int)q1.x, (int)q1.y, (int)q1.z, (int)q1.w};
        }

        f32x4 acc[4][4] = {};
        #pragma unroll
        for (int fm = 0; fm < 4; fm++)
            #pragma unroll
            for (int fn = 0; fn < 4; fn++)
                acc[fm][fn] = __builtin_amdgcn_mfma_scale_f32_16x16x128_f8f6f4(
                    af[fm], bfk[fn], acc[fm][fn],
                    0, 0,             // cbsz=fp8(e4m3), blgp=fp8(e4m3)
                    0, 0x7F,          // scale_a opsel, scale_a (e8m0 1.0)
                    0, 0x7F);         // scale_b opsel, scale_b

        #pragma unroll
        for (int fm = 0; fm < 4; fm++)
            #pragma unroll
            for (int r = 0; r < 4; r++) {
                float base = xn1[fm][r];
                #pragma unroll
                for (int fp = 0; fp < 4; fp += 2) {
                    float u = base + cn[fp]     - 2.0f * acc[fm][fp][r];
                    float v = base + cn[fp + 1] - 2.0f * acc[fm][fp + 1][r];
                    gitsum[fm][r] += (u + v) * __builtin_amdgcn_rcpf(u * v);
                }
            }

        __builtin_amdgcn_sched_barrier(0);
        __builtin_amdgcn_s_barrier();
        __builtin_amdgcn_sched_barrier(0);
    }

    #pragma unroll
    for (int fm = 0; fm < 4; fm++)
        #pragma unroll
        for (int r = 0; r < 4; r++) {
            float s = gitsum[fm][r];
            s += __shfl_xor(s, 1); s += __shfl_xor(s, 2);
            s += __shfl_xor(s, 4); s += __shfl_xor(s, 8);
            if (lr_ == 0) atomicAdd(&git_row[row0 + fm * 16 + lg * 4 + r], s);
        }

    // signal completion (release) for the reducer block
    __threadfence();
    __syncthreads();
    if (tid == 0)
        __hip_atomic_fetch_add(counter, 1, __ATOMIC_RELEASE, __HIP_MEMORY_SCOPE_AGENT);
}

extern "C" void kernel_launch(void* const* d_in, const int* in_sizes, int n_in,
                              void* d_out, int out_size, void* d_ws, size_t ws_size,
                              hipStream_t stream) {
    const float* x       = (const float*)d_in[0];
    const int*   labels  = (const int*)d_in[1];
    const float* centers = (const float*)d_in[2];
    const float* lr      = (const float*)d_in[3];

    float* ws       = (float*)d_ws;
    float* counts   = ws;
    float* sumx     = ws + 10240;
    float* git_row  = ws + 1290240;
    float* xnorm    = ws + 1298432;
    float* cent_val = ws + 1306624;
    float* cnorm    = ws + 1314816;
    int*   counter  = (int*)&counts[10200];   // zeroed with counts
    unsigned char* xb8 = (unsigned char*)d_ws + 5300224;
    unsigned char* cb8 = (unsigned char*)d_ws + 7397376;
    float* out = (float*)d_out;

    zero_ws<<<1268, 256, 0, stream>>>((float4*)d_ws);
    scatter_prep<<<B_ / 4, 256, 0, stream>>>(x, labels, counts, sumx, xnorm, xb8);
    upd_cvals<<<UPD_BLOCKS + CVAL_BLOCKS, 256, 0, stream>>>(centers, counts, sumx, cnorm, cb8, lr,
                                                            x, labels, cent_val);
    gemm_git<<<GEMM_BLOCKS + 1, 256, 0, stream>>>(xb8, cb8, xnorm, cnorm, git_row,
                                                  cent_val, out, counter);
}

// Round 18
// 50.465 us; speedup vs baseline: 1.7816x; 1.7816x over previous
//
#include <hip/hip_runtime.h>
#include <hip/hip_bf16.h>
#include <hip/hip_fp8.h>

#define B_ 8192
#define C_ 10000
#define D_ 128
#define CPAD 10112      // 158 * 64
#define NPADC 112       // CPAD - C_
#define NT_TOT 158      // 64-col tiles
#define NSTRIP 16
#define STRIPW 10       // strips 0..14 -> 10 tiles, strip 15 -> 8
#define UPD_BLOCKS 2528 // CPAD/4
#define CVAL_BLOCKS 2048// B_/4

typedef float f32x4 __attribute__((ext_vector_type(4)));
typedef int   i32x8 __attribute__((ext_vector_type(8)));

typedef const __attribute__((address_space(1))) uint32_t gu32;
typedef __attribute__((address_space(3))) uint32_t lu32;

// ---------------- ws layout (float offsets) ----------------
// counts    : [0, 10240)
// sumx      : [10240, 1290240)
// git_row   : [1290240, 1298432)
// xnorm     : [1298432, 1306624)
// cent_val  : [1306624, 1314816)
// cnorm     : [1314816, 1325056)   (CPAD, pad = 0)
// x_fp8     : byte 5,300,224  (8192 x 128 = 1 MB)
// c_fp8     : byte 7,397,376  (CPAD x 128, pad rows zero)

__global__ void zero_ws(float4* __restrict__ ws, float* __restrict__ out) {
    int idx = blockIdx.x * 256 + threadIdx.x;
    if (idx < 324608) ws[idx] = float4{0.f, 0.f, 0.f, 0.f};
    if (idx == 0) { out[0] = 0.f; out[1] = 0.f; }
}

// Fused: segment-sum atomics + fp8 cast + xnorm (single pass over x).
__global__ void scatter_prep(const float* __restrict__ x, const int* __restrict__ labels,
                             float* __restrict__ counts, float* __restrict__ sumx,
                             float* __restrict__ xnorm, unsigned char* __restrict__ xb8) {
    int tid = threadIdx.x;
    int w = tid >> 6, lane = tid & 63;
    int i = blockIdx.x * 4 + w;
    int l = labels[i];
    float2 v = *(const float2*)&x[i * D_ + lane * 2];
    atomicAdd(&sumx[l * D_ + lane * 2], v.x);
    atomicAdd(&sumx[l * D_ + lane * 2 + 1], v.y);
    if (lane == 0) atomicAdd(&counts[l], 1.0f);
    __hip_fp8_e4m3 a(v.x), b(v.y);
    unsigned short pk = (unsigned short)a.__x | ((unsigned short)b.__x << 8);
    *(unsigned short*)&xb8[i * D_ + lane * 2] = pk;
    float s = v.x * v.x + v.y * v.y;
    #pragma unroll
    for (int m = 1; m < 64; m <<= 1) s += __shfl_xor(s, m);
    if (lane == 0) xnorm[i] = s;
}

__global__ void upd_cvals(const float* __restrict__ centers, const float* __restrict__ counts,
                          const float* __restrict__ sumx, float* __restrict__ cnorm,
                          unsigned char* __restrict__ cb8, const float* __restrict__ lr,
                          const float* __restrict__ x, const int* __restrict__ labels,
                          float* __restrict__ cent_val) {
    int tid = threadIdx.x;
    int w = tid >> 6, lane = tid & 63;
    int bid = blockIdx.x;
    float lrv = lr[0];

    if (bid < UPD_BLOCKS) {
        int c = bid * 4 + w;
        if (c >= C_) {
            *(unsigned short*)&cb8[c * D_ + lane * 2] = 0;
            if (lane == 0) cnorm[c] = 0.0f;
            return;
        }
        float cnt = counts[c];
        float2 cv = *(const float2*)&centers[c * D_ + lane * 2];
        float2 sx = *(const float2*)&sumx[c * D_ + lane * 2];
        float inv = 1.0f / (1.0f + cnt);
        float nx = cv.x - lrv * (cnt * cv.x - sx.x) * inv;
        float ny = cv.y - lrv * (cnt * cv.y - sx.y) * inv;
        __hip_fp8_e4m3 a(nx), b(ny);
        unsigned short pk = (unsigned short)a.__x | ((unsigned short)b.__x << 8);
        *(unsigned short*)&cb8[c * D_ + lane * 2] = pk;
        float s = nx * nx + ny * ny;
        #pragma unroll
        for (int m = 1; m < 64; m <<= 1) s += __shfl_xor(s, m);
        if (lane == 0) cnorm[c] = s;
    } else {
        int i = (bid - UPD_BLOCKS) * 4 + w;
        int l = labels[i];
        float cnt = counts[l];
        float inv = 1.0f / (1.0f + cnt);
        float2 a  = *(const float2*)&x[i * D_ + lane * 2];
        float2 cv = *(const float2*)&centers[l * D_ + lane * 2];
        float2 sx = *(const float2*)&sumx[l * D_ + lane * 2];
        float nx = cv.x - lrv * (cnt * cv.x - sx.x) * inv;
        float ny = cv.y - lrv * (cnt * cv.y - sx.y) * inv;
        float dx = a.x - nx, dy = a.y - ny;
        float s = dx * dx + dy * dy;
        #pragma unroll
        for (int m = 1; m < 64; m <<= 1) s += __shfl_xor(s, m);
        if (lane == 0) cent_val[i] = s;
    }
}

// MX-FP8 GEMM + git: mfma_scale_f32_16x16x128_f8f6f4 (scale=1.0 const).
// K=128 in ONE MFMA; 16 MFMAs + 8 ds_read_b128 per wave-tile. 3-ring
// counted-vmcnt pipeline; no setprio (m190: null/negative on lockstep GEMM).
__global__ void __launch_bounds__(256, 2)
gemm_git(const unsigned char* __restrict__ xb8, const unsigned char* __restrict__ cb8,
         const float* __restrict__ xnorm, const float* __restrict__ cnorm,
         float* __restrict__ git_row) {
    __shared__ char ldsB[3][8192];    // 64 B-rows x 128B fp8, XOR-swizzled chunks
    __shared__ float cnLDS[STRIPW * 64];

    int tid = threadIdx.x;
    int w = tid >> 6, lane = tid & 63;
    int lr_ = lane & 15, lg = lane >> 4;
    int bm = blockIdx.x;              // 0..31
    int strip = blockIdx.y;           // 0..15
    int row0 = bm * 256 + w * 64;
    int bn0 = strip * STRIPW;
    int nt = (strip == NSTRIP - 1) ? (NT_TOT - bn0) : STRIPW;

    // A fragments: lane holds row (row0+f*16+lr_), k-bytes [lg*32, +32); pinned.
    i32x8 af[4];
    #pragma unroll
    for (int f = 0; f < 4; f++) {
        const uint4* pa = (const uint4*)(xb8 + (size_t)(row0 + f * 16 + lr_) * 128 + lg * 32);
        uint4 u0 = pa[0], u1 = pa[1];
        asm volatile("" : "+v"(u0.x), "+v"(u0.y), "+v"(u0.z), "+v"(u0.w),
                          "+v"(u1.x), "+v"(u1.y), "+v"(u1.z), "+v"(u1.w));
        af[f] = i32x8{(int)u0.x, (int)u0.y, (int)u0.z, (int)u0.w,
                      (int)u1.x, (int)u1.y, (int)u1.z, (int)u1.w};
    }

    float xn1[4][4];
    #pragma unroll
    for (int fm = 0; fm < 4; fm++)
        #pragma unroll
        for (int r = 0; r < 4; r++) {
            float v = 1.0f + xnorm[row0 + fm * 16 + lg * 4 + r];
            asm volatile("" : "+v"(v));
            xn1[fm][r] = v;
        }

    float gitsum[4][4] = {};

    // stage: tile = 64 rows x 128B = 512 16B-slots; 256 threads cover 2 each.
    // slot s -> row=s>>3, ch=s&7; source chunk = ch ^ (row&7) (pre-swizzle).
    const char* gB = (const char*)cb8;
    int sr0 = tid >> 3,          sc0 = (tid & 7) ^ (sr0 & 7);
    int sr1 = (tid + 256) >> 3,  sc1 = ((tid + 256) & 7) ^ (sr1 & 7);
    size_t goff0 = (size_t)sr0 * 128 + sc0 * 16;
    size_t goff1 = (size_t)sr1 * 128 + sc1 * 16;

    auto stage = [&](int t, int buf) {
        const char* base = gB + (size_t)(bn0 + t) * 64 * 128;   // tile = 64 x 128B
        __builtin_amdgcn_global_load_lds((gu32*)(base + goff0),
                                         (lu32*)&ldsB[buf][tid * 16], 16, 0, 0);
        __builtin_amdgcn_global_load_lds((gu32*)(base + goff1),
                                         (lu32*)&ldsB[buf][4096 + tid * 16], 16, 0, 0);
    };

    // prologue: cnorm -> LDS, stage tiles 0 and 1; single full drain.
    for (int i = tid; i < nt * 64; i += 256) cnLDS[i] = cnorm[bn0 * 64 + i];
    stage(0, 0);
    if (nt > 1) stage(1, 1);
    __syncthreads();

    for (int t = 0; t < nt; ++t) {
        int bc = t % 3;
        if (t + 2 < nt) stage(t + 2, (t + 2) % 3);

        if (t + 2 < nt)      asm volatile("s_waitcnt vmcnt(4)" ::: "memory");
        else if (t + 1 < nt) asm volatile("s_waitcnt vmcnt(2)" ::: "memory");
        else                 asm volatile("s_waitcnt vmcnt(0)" ::: "memory");
        __builtin_amdgcn_sched_barrier(0);
        __builtin_amdgcn_s_barrier();
        __builtin_amdgcn_sched_barrier(0);

        float cn[4];
        #pragma unroll
        for (int fn = 0; fn < 4; fn++) cn[fn] = cnLDS[t * 64 + fn * 16 + lr_];

        // B fragments: col-row = fn*16+lr_, k-bytes [lg*32, +32) (2 chunks).
        i32x8 bfk[4];
        int r7 = lr_ & 7;
        #pragma unroll
        for (int fn = 0; fn < 4; fn++) {
            const char* rowp = &ldsB[bc][(fn * 16 + lr_) * 128];
            uint4 q0 = *(const uint4*)(rowp + (((lg * 2)     ^ r7) * 16));
            uint4 q1 = *(const uint4*)(rowp + (((lg * 2 + 1) ^ r7) * 16));
            bfk[fn] = i32x8{(int)q0.x, (int)q0.y, (int)q0.z, (int)q0.w,
                            (int)q1.x, (int)q1.y, (int)q1.z, (int)q1.w};
        }

        f32x4 acc[4][4] = {};
        #pragma unroll
        for (int fm = 0; fm < 4; fm++)
            #pragma unroll
            for (int fn = 0; fn < 4; fn++)
                acc[fm][fn] = __builtin_amdgcn_mfma_scale_f32_16x16x128_f8f6f4(
                    af[fm], bfk[fn], acc[fm][fn],
                    0, 0,             // cbsz=fp8(e4m3), blgp=fp8(e4m3)
                    0, 0x7F,          // scale_a opsel, scale_a (e8m0 1.0)
                    0, 0x7F);         // scale_b opsel, scale_b

        #pragma unroll
        for (int fm = 0; fm < 4; fm++)
            #pragma unroll
            for (int r = 0; r < 4; r++) {
                float base = xn1[fm][r];
                #pragma unroll
                for (int fp = 0; fp < 4; fp += 2) {
                    float u = base + cn[fp]     - 2.0f * acc[fm][fp][r];
                    float v = base + cn[fp + 1] - 2.0f * acc[fm][fp + 1][r];
                    gitsum[fm][r] += (u + v) * __builtin_amdgcn_rcpf(u * v);
                }
            }

        __builtin_amdgcn_sched_barrier(0);
        __builtin_amdgcn_s_barrier();
        __builtin_amdgcn_sched_barrier(0);
    }

    #pragma unroll
    for (int fm = 0; fm < 4; fm++)
        #pragma unroll
        for (int r = 0; r < 4; r++) {
            float s = gitsum[fm][r];
            s += __shfl_xor(s, 1); s += __shfl_xor(s, 2);
            s += __shfl_xor(s, 4); s += __shfl_xor(s, 8);
            if (lr_ == 0) atomicAdd(&git_row[row0 + fm * 16 + lg * 4 + r], s);
        }
}

__global__ void final_reduce(const float* __restrict__ cent_val, const float* __restrict__ git_row,
                             const float* __restrict__ xnorm, float* __restrict__ out) {
    int tid = threadIdx.x;
    int i = blockIdx.x * 256 + tid;
    float c = cent_val[i];
    float cl = fminf(fmaxf(c, 1e-12f), 1e12f);
    float g = git_row[i] - 1.0f / (1.0f + c) - (float)NPADC / (1.0f + xnorm[i]);
    float gl = fminf(fmaxf(g, 1e-12f), 1e12f);
    #pragma unroll
    for (int m = 1; m < 64; m <<= 1) { cl += __shfl_xor(cl, m); gl += __shfl_xor(gl, m); }
    __shared__ float scl[4], sgl[4];
    if ((tid & 63) == 0) { scl[tid >> 6] = cl; sgl[tid >> 6] = gl; }
    __syncthreads();
    if (tid == 0) {
        float a = scl[0] + scl[1] + scl[2] + scl[3];
        float b = sgl[0] + sgl[1] + sgl[2] + sgl[3];
        atomicAdd(&out[0], a / (float)B_);
        atomicAdd(&out[1], b / (float)B_);
    }
}

extern "C" void kernel_launch(void* const* d_in, const int* in_sizes, int n_in,
                              void* d_out, int out_size, void* d_ws, size_t ws_size,
                              hipStream_t stream) {
    const float* x       = (const float*)d_in[0];
    const int*   labels  = (const int*)d_in[1];
    const float* centers = (const float*)d_in[2];
    const float* lr      = (const float*)d_in[3];

    float* ws       = (float*)d_ws;
    float* counts   = ws;
    float* sumx     = ws + 10240;
    float* git_row  = ws + 1290240;
    float* xnorm    = ws + 1298432;
    float* cent_val = ws + 1306624;
    float* cnorm    = ws + 1314816;
    unsigned char* xb8 = (unsigned char*)d_ws + 5300224;
    unsigned char* cb8 = (unsigned char*)d_ws + 7397376;
    float* out = (float*)d_out;

    zero_ws<<<1268, 256, 0, stream>>>((float4*)d_ws, out);
    scatter_prep<<<B_ / 4, 256, 0, stream>>>(x, labels, counts, sumx, xnorm, xb8);
    upd_cvals<<<UPD_BLOCKS + CVAL_BLOCKS, 256, 0, stream>>>(centers, counts, sumx, cnorm, cb8, lr,
                                                            x, labels, cent_val);
    gemm_git<<<dim3(32, NSTRIP), 256, 0, stream>>>(xb8, cb8, xnorm, cnorm, git_row);
    final_reduce<<<32, 256, 0, stream>>>(cent_val, git_row, xnorm, out);
}

// Round 19
// 50.332 us; speedup vs baseline: 1.7863x; 1.0026x over previous
//
#include <hip/hip_runtime.h>
#include <hip/hip_bf16.h>
#include <hip/hip_fp8.h>

#define B_ 8192
#define C_ 10000
#define D_ 128
#define CPAD 10112      // 158 * 64
#define NPADC 112       // CPAD - C_
#define NT_TOT 158      // 64-col tiles
#define NSTRIP 16
#define STRIPW 10       // strips 0..14 -> 10 tiles, strip 15 -> 8
#define UPD_BLOCKS 2528 // CPAD/4
#define CVAL_BLOCKS 2048// B_/4

typedef float f32x4 __attribute__((ext_vector_type(4)));
typedef int   i32x8 __attribute__((ext_vector_type(8)));

typedef const __attribute__((address_space(1))) uint32_t gu32;
typedef __attribute__((address_space(3))) uint32_t lu32;

// ---------------- ws layout (float offsets) ----------------
// counts    : [0, 10240)
// sumx      : [10240, 1290240)
// git_row   : [1290240, 1298432)
// xnorm     : [1298432, 1306624)
// cent_val  : [1306624, 1314816)
// cnorm     : [1314816, 1325056)   (CPAD, pad = 0)
// x_fp8     : byte 5,300,224  (8192 x 128 = 1 MB)
// c_fp8     : byte 7,397,376  (CPAD x 128, pad rows zero)

__global__ void zero_ws(float4* __restrict__ ws, float* __restrict__ out) {
    int idx = blockIdx.x * 256 + threadIdx.x;
    if (idx < 324608) ws[idx] = float4{0.f, 0.f, 0.f, 0.f};
    if (idx == 0) { out[0] = 0.f; out[1] = 0.f; }
}

// Fused: segment-sum atomics + fp8 cast + xnorm (single pass over x).
__global__ void scatter_prep(const float* __restrict__ x, const int* __restrict__ labels,
                             float* __restrict__ counts, float* __restrict__ sumx,
                             float* __restrict__ xnorm, unsigned char* __restrict__ xb8) {
    int tid = threadIdx.x;
    int w = tid >> 6, lane = tid & 63;
    int i = blockIdx.x * 4 + w;
    int l = labels[i];
    float2 v = *(const float2*)&x[i * D_ + lane * 2];
    atomicAdd(&sumx[l * D_ + lane * 2], v.x);
    atomicAdd(&sumx[l * D_ + lane * 2 + 1], v.y);
    if (lane == 0) atomicAdd(&counts[l], 1.0f);
    __hip_fp8_e4m3 a(v.x), b(v.y);
    unsigned short pk = (unsigned short)a.__x | ((unsigned short)b.__x << 8);
    *(unsigned short*)&xb8[i * D_ + lane * 2] = pk;
    float s = v.x * v.x + v.y * v.y;
    #pragma unroll
    for (int m = 1; m < 64; m <<= 1) s += __shfl_xor(s, m);
    if (lane == 0) xnorm[i] = s;
}

__global__ void upd_cvals(const float* __restrict__ centers, const float* __restrict__ counts,
                          const float* __restrict__ sumx, float* __restrict__ cnorm,
                          unsigned char* __restrict__ cb8, const float* __restrict__ lr,
                          const float* __restrict__ x, const int* __restrict__ labels,
                          float* __restrict__ cent_val) {
    int tid = threadIdx.x;
    int w = tid >> 6, lane = tid & 63;
    int bid = blockIdx.x;
    float lrv = lr[0];

    if (bid < UPD_BLOCKS) {
        int c = bid * 4 + w;
        if (c >= C_) {
            *(unsigned short*)&cb8[c * D_ + lane * 2] = 0;
            if (lane == 0) cnorm[c] = 0.0f;
            return;
        }
        float cnt = counts[c];
        float2 cv = *(const float2*)&centers[c * D_ + lane * 2];
        float2 sx = *(const float2*)&sumx[c * D_ + lane * 2];
        float inv = 1.0f / (1.0f + cnt);
        float nx = cv.x - lrv * (cnt * cv.x - sx.x) * inv;
        float ny = cv.y - lrv * (cnt * cv.y - sx.y) * inv;
        __hip_fp8_e4m3 a(nx), b(ny);
        unsigned short pk = (unsigned short)a.__x | ((unsigned short)b.__x << 8);
        *(unsigned short*)&cb8[c * D_ + lane * 2] = pk;
        float s = nx * nx + ny * ny;
        #pragma unroll
        for (int m = 1; m < 64; m <<= 1) s += __shfl_xor(s, m);
        if (lane == 0) cnorm[c] = s;
    } else {
        int i = (bid - UPD_BLOCKS) * 4 + w;
        int l = labels[i];
        float cnt = counts[l];
        float inv = 1.0f / (1.0f + cnt);
        float2 a  = *(const float2*)&x[i * D_ + lane * 2];
        float2 cv = *(const float2*)&centers[l * D_ + lane * 2];
        float2 sx = *(const float2*)&sumx[l * D_ + lane * 2];
        float nx = cv.x - lrv * (cnt * cv.x - sx.x) * inv;
        float ny = cv.y - lrv * (cnt * cv.y - sx.y) * inv;
        float dx = a.x - nx, dy = a.y - ny;
        float s = dx * dx + dy * dy;
        #pragma unroll
        for (int m = 1; m < 64; m <<= 1) s += __shfl_xor(s, m);
        if (lane == 0) cent_val[i] = s;
    }
}

// MX-FP8 GEMM + git: R18 core with ONE barrier per tile.
// Order: vmcnt(stage(t) landed) -> s_barrier -> stage(t+2) -> compute.
// WAR-safe: stage(t+2)'s ring slot was last read at tile t-1, and every wave
// passed barrier(t) only after finishing tile t-1's reads.
__global__ void __launch_bounds__(256, 2)
gemm_git(const unsigned char* __restrict__ xb8, const unsigned char* __restrict__ cb8,
         const float* __restrict__ xnorm, const float* __restrict__ cnorm,
         float* __restrict__ git_row) {
    __shared__ char ldsB[3][8192];    // 64 B-rows x 128B fp8, XOR-swizzled chunks
    __shared__ float cnLDS[STRIPW * 64];

    int tid = threadIdx.x;
    int w = tid >> 6, lane = tid & 63;
    int lr_ = lane & 15, lg = lane >> 4;
    int bm = blockIdx.x;              // 0..31
    int strip = blockIdx.y;           // 0..15
    int row0 = bm * 256 + w * 64;
    int bn0 = strip * STRIPW;
    int nt = (strip == NSTRIP - 1) ? (NT_TOT - bn0) : STRIPW;

    // A fragments: lane holds row (row0+f*16+lr_), k-bytes [lg*32, +32); pinned.
    i32x8 af[4];
    #pragma unroll
    for (int f = 0; f < 4; f++) {
        const uint4* pa = (const uint4*)(xb8 + (size_t)(row0 + f * 16 + lr_) * 128 + lg * 32);
        uint4 u0 = pa[0], u1 = pa[1];
        asm volatile("" : "+v"(u0.x), "+v"(u0.y), "+v"(u0.z), "+v"(u0.w),
                          "+v"(u1.x), "+v"(u1.y), "+v"(u1.z), "+v"(u1.w));
        af[f] = i32x8{(int)u0.x, (int)u0.y, (int)u0.z, (int)u0.w,
                      (int)u1.x, (int)u1.y, (int)u1.z, (int)u1.w};
    }

    float xn1[4][4];
    #pragma unroll
    for (int fm = 0; fm < 4; fm++)
        #pragma unroll
        for (int r = 0; r < 4; r++) {
            float v = 1.0f + xnorm[row0 + fm * 16 + lg * 4 + r];
            asm volatile("" : "+v"(v));
            xn1[fm][r] = v;
        }

    float gitsum[4][4] = {};

    // stage: tile = 64 rows x 128B = 512 16B-slots; 256 threads cover 2 each.
    const char* gB = (const char*)cb8;
    int sr0 = tid >> 3,          sc0 = (tid & 7) ^ (sr0 & 7);
    int sr1 = (tid + 256) >> 3,  sc1 = ((tid + 256) & 7) ^ (sr1 & 7);
    size_t goff0 = (size_t)sr0 * 128 + sc0 * 16;
    size_t goff1 = (size_t)sr1 * 128 + sc1 * 16;

    auto stage = [&](int t, int buf) {
        const char* base = gB + (size_t)(bn0 + t) * 64 * 128;   // tile = 64 x 128B
        __builtin_amdgcn_global_load_lds((gu32*)(base + goff0),
                                         (lu32*)&ldsB[buf][tid * 16], 16, 0, 0);
        __builtin_amdgcn_global_load_lds((gu32*)(base + goff1),
                                         (lu32*)&ldsB[buf][4096 + tid * 16], 16, 0, 0);
    };

    // prologue: cnorm -> LDS, stage tiles 0 and 1; single full drain.
    for (int i = tid; i < nt * 64; i += 256) cnLDS[i] = cnorm[bn0 * 64 + i];
    stage(0, 0);
    if (nt > 1) stage(1, 1);
    __syncthreads();

    for (int t = 0; t < nt; ++t) {
        int bc = t % 3;

        // stage(t) landed; stage(t+1)'s 2 loads may stay in flight.
        if (t + 1 < nt) asm volatile("s_waitcnt vmcnt(2)" ::: "memory");
        else            asm volatile("s_waitcnt vmcnt(0)" ::: "memory");
        __builtin_amdgcn_sched_barrier(0);
        __builtin_amdgcn_s_barrier();     // single barrier per tile
        __builtin_amdgcn_sched_barrier(0);

        // issue next-next stage AFTER the barrier (slot's readers are done)
        if (t + 2 < nt) stage(t + 2, (t + 2) % 3);

        float cn[4];
        #pragma unroll
        for (int fn = 0; fn < 4; fn++) cn[fn] = cnLDS[t * 64 + fn * 16 + lr_];

        // B fragments: col-row = fn*16+lr_, k-bytes [lg*32, +32) (2 chunks).
        i32x8 bfk[4];
        int r7 = lr_ & 7;
        #pragma unroll
        for (int fn = 0; fn < 4; fn++) {
            const char* rowp = &ldsB[bc][(fn * 16 + lr_) * 128];
            uint4 q0 = *(const uint4*)(rowp + (((lg * 2)     ^ r7) * 16));
            uint4 q1 = *(const uint4*)(rowp + (((lg * 2 + 1) ^ r7) * 16));
            bfk[fn] = i32x8{(int)q0.x, (int)q0.y, (int)q0.z, (int)q0.w,
                            (int)q1.x, (int)q1.y, (int)q1.z, (int)q1.w};
        }

        f32x4 acc[4][4] = {};
        #pragma unroll
        for (int fm = 0; fm < 4; fm++)
            #pragma unroll
            for (int fn = 0; fn < 4; fn++)
                acc[fm][fn] = __builtin_amdgcn_mfma_scale_f32_16x16x128_f8f6f4(
                    af[fm], bfk[fn], acc[fm][fn],
                    0, 0,             // cbsz=fp8(e4m3), blgp=fp8(e4m3)
                    0, 0x7F,          // scale_a opsel, scale_a (e8m0 1.0)
                    0, 0x7F);         // scale_b opsel, scale_b

        #pragma unroll
        for (int fm = 0; fm < 4; fm++)
            #pragma unroll
            for (int r = 0; r < 4; r++) {
                float base = xn1[fm][r];
                #pragma unroll
                for (int fp = 0; fp < 4; fp += 2) {
                    float u = base + cn[fp]     - 2.0f * acc[fm][fp][r];
                    float v = base + cn[fp + 1] - 2.0f * acc[fm][fp + 1][r];
                    gitsum[fm][r] += (u + v) * __builtin_amdgcn_rcpf(u * v);
                }
            }
        // no trailing barrier: next iteration's barrier orders ring reuse
    }

    #pragma unroll
    for (int fm = 0; fm < 4; fm++)
        #pragma unroll
        for (int r = 0; r < 4; r++) {
            float s = gitsum[fm][r];
            s += __shfl_xor(s, 1); s += __shfl_xor(s, 2);
            s += __shfl_xor(s, 4); s += __shfl_xor(s, 8);
            if (lr_ == 0) atomicAdd(&git_row[row0 + fm * 16 + lg * 4 + r], s);
        }
}

__global__ void final_reduce(const float* __restrict__ cent_val, const float* __restrict__ git_row,
                             const float* __restrict__ xnorm, float* __restrict__ out) {
    int tid = threadIdx.x;
    int i = blockIdx.x * 256 + tid;
    float c = cent_val[i];
    float cl = fminf(fmaxf(c, 1e-12f), 1e12f);
    float g = git_row[i] - 1.0f / (1.0f + c) - (float)NPADC / (1.0f + xnorm[i]);
    float gl = fminf(fmaxf(g, 1e-12f), 1e12f);
    #pragma unroll
    for (int m = 1; m < 64; m <<= 1) { cl += __shfl_xor(cl, m); gl += __shfl_xor(gl, m); }
    __shared__ float scl[4], sgl[4];
    if ((tid & 63) == 0) { scl[tid >> 6] = cl; sgl[tid >> 6] = gl; }
    __syncthreads();
    if (tid == 0) {
        float a = scl[0] + scl[1] + scl[2] + scl[3];
        float b = sgl[0] + sgl[1] + sgl[2] + sgl[3];
        atomicAdd(&out[0], a / (float)B_);
        atomicAdd(&out[1], b / (float)B_);
    }
}

extern "C" void kernel_launch(void* const* d_in, const int* in_sizes, int n_in,
                              void* d_out, int out_size, void* d_ws, size_t ws_size,
                              hipStream_t stream) {
    const float* x       = (const float*)d_in[0];
    const int*   labels  = (const int*)d_in[1];
    const float* centers = (const float*)d_in[2];
    const float* lr      = (const float*)d_in[3];

    float* ws       = (float*)d_ws;
    float* counts   = ws;
    float* sumx     = ws + 10240;
    float* git_row  = ws + 1290240;
    float* xnorm    = ws + 1298432;
    float* cent_val = ws + 1306624;
    float* cnorm    = ws + 1314816;
    unsigned char* xb8 = (unsigned char*)d_ws + 5300224;
    unsigned char* cb8 = (unsigned char*)d_ws + 7397376;
    float* out = (float*)d_out;

    zero_ws<<<1268, 256, 0, stream>>>((float4*)d_ws, out);
    scatter_prep<<<B_ / 4, 256, 0, stream>>>(x, labels, counts, sumx, xnorm, xb8);
    upd_cvals<<<UPD_BLOCKS + CVAL_BLOCKS, 256, 0, stream>>>(centers, counts, sumx, cnorm, cb8, lr,
                                                            x, labels, cent_val);
    gemm_git<<<dim3(32, NSTRIP), 256, 0, stream>>>(xb8, cb8, xnorm, cnorm, git_row);
    final_reduce<<<32, 256, 0, stream>>>(cent_val, git_row, xnorm, out);
}

// Round 20
// 47.417 us; speedup vs baseline: 1.8961x; 1.0615x over previous
//
#include <hip/hip_runtime.h>
#include <hip/hip_bf16.h>

#define B_ 8192
#define C_ 10000
#define D_ 128
#define CPAD 10112      // 158 * 64
#define NPADC 112       // CPAD - C_
#define NT_TOT 158      // 64-col tiles
#define NSTRIP 16
#define STRIPW 10       // strips 0..14 -> 10 tiles, strip 15 -> 8
#define UPD_BLOCKS 2528 // CPAD/4
#define CVAL_BLOCKS 2048// B_/4

typedef float f32x4 __attribute__((ext_vector_type(4)));
typedef int   i32x8 __attribute__((ext_vector_type(8)));

typedef const __attribute__((address_space(1))) uint32_t gu32;
typedef __attribute__((address_space(3))) uint32_t lu32;

// ---------------- ws layout (float offsets) ----------------
// counts    : [0, 10240)
// sumx      : [10240, 1290240)
// git_row   : [1290240, 1298432)
// xnorm     : [1298432, 1306624)
// cent_val  : [1306624, 1314816)
// cnorm     : [1314816, 1325056)   (CPAD, pad = 0)
// x_fp4     : byte 5,300,224  (8192 x 64B = 512 KB)
// c_fp4     : byte 7,397,376  (CPAD x 64B = 632 KB, pad rows zero)

// branchless-ish float -> e2m1 code (grid 0,.5,1,1.5,2,3,4,6; RTN)
__device__ inline unsigned fp4q(float v) {
    float m = fabsf(v);
    unsigned s = (__float_as_uint(v) >> 31) << 3;
    unsigned c;
    if      (m < 0.25f) c = 0;
    else if (m < 0.75f) c = 1;
    else if (m < 1.25f) c = 2;
    else if (m < 1.75f) c = 3;
    else if (m < 2.5f)  c = 4;
    else if (m < 3.5f)  c = 5;
    else if (m < 5.0f)  c = 6;
    else                c = 7;
    return s | c;
}

__global__ void zero_ws(float4* __restrict__ ws, float* __restrict__ out) {
    int idx = blockIdx.x * 256 + threadIdx.x;
    if (idx < 324608) ws[idx] = float4{0.f, 0.f, 0.f, 0.f};
    if (idx == 0) { out[0] = 0.f; out[1] = 0.f; }
}

// Fused: segment-sum atomics + fp4 cast + xnorm (single pass over x).
__global__ void scatter_prep(const float* __restrict__ x, const int* __restrict__ labels,
                             float* __restrict__ counts, float* __restrict__ sumx,
                             float* __restrict__ xnorm, unsigned char* __restrict__ xb4) {
    int tid = threadIdx.x;
    int w = tid >> 6, lane = tid & 63;
    int i = blockIdx.x * 4 + w;
    int l = labels[i];
    float2 v = *(const float2*)&x[i * D_ + lane * 2];
    atomicAdd(&sumx[l * D_ + lane * 2], v.x);
    atomicAdd(&sumx[l * D_ + lane * 2 + 1], v.y);
    if (lane == 0) atomicAdd(&counts[l], 1.0f);
    xb4[i * 64 + lane] = (unsigned char)(fp4q(v.x) | (fp4q(v.y) << 4));
    float s = v.x * v.x + v.y * v.y;
    #pragma unroll
    for (int m = 1; m < 64; m <<= 1) s += __shfl_xor(s, m);
    if (lane == 0) xnorm[i] = s;
}

__global__ void upd_cvals(const float* __restrict__ centers, const float* __restrict__ counts,
                          const float* __restrict__ sumx, float* __restrict__ cnorm,
                          unsigned char* __restrict__ cb4, const float* __restrict__ lr,
                          const float* __restrict__ x, const int* __restrict__ labels,
                          float* __restrict__ cent_val) {
    int tid = threadIdx.x;
    int w = tid >> 6, lane = tid & 63;
    int bid = blockIdx.x;
    float lrv = lr[0];

    if (bid < UPD_BLOCKS) {
        int c = bid * 4 + w;
        if (c >= C_) {
            cb4[c * 64 + lane] = 0;
            if (lane == 0) cnorm[c] = 0.0f;
            return;
        }
        float cnt = counts[c];
        float2 cv = *(const float2*)&centers[c * D_ + lane * 2];
        float2 sx = *(const float2*)&sumx[c * D_ + lane * 2];
        float inv = 1.0f / (1.0f + cnt);
        float nx = cv.x - lrv * (cnt * cv.x - sx.x) * inv;
        float ny = cv.y - lrv * (cnt * cv.y - sx.y) * inv;
        cb4[c * 64 + lane] = (unsigned char)(fp4q(nx) | (fp4q(ny) << 4));
        float s = nx * nx + ny * ny;
        #pragma unroll
        for (int m = 1; m < 64; m <<= 1) s += __shfl_xor(s, m);
        if (lane == 0) cnorm[c] = s;
    } else {
        int i = (bid - UPD_BLOCKS) * 4 + w;
        int l = labels[i];
        float cnt = counts[l];
        float inv = 1.0f / (1.0f + cnt);
        float2 a  = *(const float2*)&x[i * D_ + lane * 2];
        float2 cv = *(const float2*)&centers[l * D_ + lane * 2];
        float2 sx = *(const float2*)&sumx[l * D_ + lane * 2];
        float nx = cv.x - lrv * (cnt * cv.x - sx.x) * inv;
        float ny = cv.y - lrv * (cnt * cv.y - sx.y) * inv;
        float dx = a.x - nx, dy = a.y - ny;
        float s = dx * dx + dy * dy;
        #pragma unroll
        for (int m = 1; m < 64; m <<= 1) s += __shfl_xor(s, m);
        if (lane == 0) cent_val[i] = s;
    }
}

// MX-FP4 GEMM + git: mfma_scale_f32_16x16x128_f8f6f4 with cbsz=blgp=4 (e2m1),
// scale=1.0. A-frag 16B/lane (regs 0-3); B tile 4KB; 3-ring, single barrier
// per tile (R19 structure), counted vmcnt (1 load/stage).
__global__ void __launch_bounds__(256, 2)
gemm_git(const unsigned char* __restrict__ xb4, const unsigned char* __restrict__ cb4,
         const float* __restrict__ xnorm, const float* __restrict__ cnorm,
         float* __restrict__ git_row) {
    __shared__ char ldsB[3][4096];    // 64 B-rows x 64B fp4, swizzled chunks
    __shared__ float cnLDS[STRIPW * 64];

    int tid = threadIdx.x;
    int w = tid >> 6, lane = tid & 63;
    int lr_ = lane & 15, lg = lane >> 4;
    int bm = blockIdx.x;              // 0..31
    int strip = blockIdx.y;           // 0..15
    int row0 = bm * 256 + w * 64;
    int bn0 = strip * STRIPW;
    int nt = (strip == NSTRIP - 1) ? (NT_TOT - bn0) : STRIPW;

    // A fragments: lane holds row (row0+f*16+lr_), K-elems [lg*32,+32) =
    // 16 bytes at offset lg*16; regs 4-7 zero. Pinned.
    i32x8 af[4];
    #pragma unroll
    for (int f = 0; f < 4; f++) {
        const uint4* pa = (const uint4*)(xb4 + (size_t)(row0 + f * 16 + lr_) * 64 + lg * 16);
        uint4 u0 = pa[0];
        asm volatile("" : "+v"(u0.x), "+v"(u0.y), "+v"(u0.z), "+v"(u0.w));
        af[f] = i32x8{(int)u0.x, (int)u0.y, (int)u0.z, (int)u0.w, 0, 0, 0, 0};
    }

    float xn1[4][4];
    #pragma unroll
    for (int fm = 0; fm < 4; fm++)
        #pragma unroll
        for (int r = 0; r < 4; r++) {
            float v = 1.0f + xnorm[row0 + fm * 16 + lg * 4 + r];
            asm volatile("" : "+v"(v));
            xn1[fm][r] = v;
        }

    float gitsum[4][4] = {};

    // stage: tile = 64 rows x 64B = 256 16B-slots; 1 slot/thread.
    // slot tid -> row = tid>>2, c' = tid&3; src chunk = c' ^ ((row>>1)&3).
    const char* gB = (const char*)cb4;
    {
    }
    int srow = tid >> 2;
    int sc = (tid & 3) ^ ((srow >> 1) & 3);
    size_t goff = (size_t)srow * 64 + sc * 16;

    auto stage = [&](int t, int buf) {
        const char* base = gB + (size_t)(bn0 + t) * 64 * 64;    // tile = 64 x 64B
        __builtin_amdgcn_global_load_lds((gu32*)(base + goff),
                                         (lu32*)&ldsB[buf][tid * 16], 16, 0, 0);
    };

    // prologue: cnorm -> LDS, stage tiles 0 and 1; single full drain.
    for (int i = tid; i < nt * 64; i += 256) cnLDS[i] = cnorm[bn0 * 64 + i];
    stage(0, 0);
    if (nt > 1) stage(1, 1);
    __syncthreads();

    for (int t = 0; t < nt; ++t) {
        int bc = t % 3;

        // stage(t) landed; stage(t+1)'s load may stay in flight.
        if (t + 1 < nt) asm volatile("s_waitcnt vmcnt(1)" ::: "memory");
        else            asm volatile("s_waitcnt vmcnt(0)" ::: "memory");
        __builtin_amdgcn_sched_barrier(0);
        __builtin_amdgcn_s_barrier();     // single barrier per tile
        __builtin_amdgcn_sched_barrier(0);

        // issue next-next stage AFTER the barrier (slot's readers are done)
        if (t + 2 < nt) stage(t + 2, (t + 2) % 3);

        float cn[4];
        #pragma unroll
        for (int fn = 0; fn < 4; fn++) cn[fn] = cnLDS[t * 64 + fn * 16 + lr_];

        // B fragments: col-row = fn*16+lr_; chunk' = lg ^ ((lr_>>1)&3).
        i32x8 bfk[4];
        int cpr = ((lr_ >> 1) & 3);
        #pragma unroll
        for (int fn = 0; fn < 4; fn++) {
            const char* rowp = &ldsB[bc][(fn * 16 + lr_) * 64];
            uint4 q0 = *(const uint4*)(rowp + ((lg ^ cpr) & 3) * 16);
            bfk[fn] = i32x8{(int)q0.x, (int)q0.y, (int)q0.z, (int)q0.w, 0, 0, 0, 0};
        }

        f32x4 acc[4][4] = {};
        #pragma unroll
        for (int fm = 0; fm < 4; fm++)
            #pragma unroll
            for (int fn = 0; fn < 4; fn++)
                acc[fm][fn] = __builtin_amdgcn_mfma_scale_f32_16x16x128_f8f6f4(
                    af[fm], bfk[fn], acc[fm][fn],
                    4, 4,             // cbsz=fp4(e2m1), blgp=fp4(e2m1)
                    0, 0x7F,          // scale_a opsel, scale_a (e8m0 1.0)
                    0, 0x7F);         // scale_b opsel, scale_b

        #pragma unroll
        for (int fm = 0; fm < 4; fm++)
            #pragma unroll
            for (int r = 0; r < 4; r++) {
                float base = xn1[fm][r];
                #pragma unroll
                for (int fp = 0; fp < 4; fp += 2) {
                    float u = base + cn[fp]     - 2.0f * acc[fm][fp][r];
                    float v = base + cn[fp + 1] - 2.0f * acc[fm][fp + 1][r];
                    gitsum[fm][r] += (u + v) * __builtin_amdgcn_rcpf(u * v);
                }
            }
        // no trailing barrier: next iteration's barrier orders ring reuse
    }

    #pragma unroll
    for (int fm = 0; fm < 4; fm++)
        #pragma unroll
        for (int r = 0; r < 4; r++) {
            float s = gitsum[fm][r];
            s += __shfl_xor(s, 1); s += __shfl_xor(s, 2);
            s += __shfl_xor(s, 4); s += __shfl_xor(s, 8);
            if (lr_ == 0) atomicAdd(&git_row[row0 + fm * 16 + lg * 4 + r], s);
        }
}

__global__ void final_reduce(const float* __restrict__ cent_val, const float* __restrict__ git_row,
                             const float* __restrict__ xnorm, float* __restrict__ out) {
    int tid = threadIdx.x;
    int i = blockIdx.x * 256 + tid;
    float c = cent_val[i];
    float cl = fminf(fmaxf(c, 1e-12f), 1e12f);
    float g = git_row[i] - 1.0f / (1.0f + c) - (float)NPADC / (1.0f + xnorm[i]);
    float gl = fminf(fmaxf(g, 1e-12f), 1e12f);
    #pragma unroll
    for (int m = 1; m < 64; m <<= 1) { cl += __shfl_xor(cl, m); gl += __shfl_xor(gl, m); }
    __shared__ float scl[4], sgl[4];
    if ((tid & 63) == 0) { scl[tid >> 6] = cl; sgl[tid >> 6] = gl; }
    __syncthreads();
    if (tid == 0) {
        float a = scl[0] + scl[1] + scl[2] + scl[3];
        float b = sgl[0] + sgl[1] + sgl[2] + sgl[3];
        atomicAdd(&out[0], a / (float)B_);
        atomicAdd(&out[1], b / (float)B_);
    }
}

extern "C" void kernel_launch(void* const* d_in, const int* in_sizes, int n_in,
                              void* d_out, int out_size, void* d_ws, size_t ws_size,
                              hipStream_t stream) {
    const float* x       = (const float*)d_in[0];
    const int*   labels  = (const int*)d_in[1];
    const float* centers = (const float*)d_in[2];
    const float* lr      = (const float*)d_in[3];

    float* ws       = (float*)d_ws;
    float* counts   = ws;
    float* sumx     = ws + 10240;
    float* git_row  = ws + 1290240;
    float* xnorm    = ws + 1298432;
    float* cent_val = ws + 1306624;
    float* cnorm    = ws + 1314816;
    unsigned char* xb4 = (unsigned char*)d_ws + 5300224;
    unsigned char* cb4 = (unsigned char*)d_ws + 7397376;
    float* out = (float*)d_out;

    zero_ws<<<1268, 256, 0, stream>>>((float4*)d_ws, out);
    scatter_prep<<<B_ / 4, 256, 0, stream>>>(x, labels, counts, sumx, xnorm, xb4);
    upd_cvals<<<UPD_BLOCKS + CVAL_BLOCKS, 256, 0, stream>>>(centers, counts, sumx, cnorm, cb4, lr,
                                                            x, labels, cent_val);
    gemm_git<<<dim3(32, NSTRIP), 256, 0, stream>>>(xb4, cb4, xnorm, cnorm, git_row);
    final_reduce<<<32, 256, 0, stream>>>(cent_val, git_row, xnorm, out);
}

// Round 21
// 46.492 us; speedup vs baseline: 1.9339x; 1.0199x over previous
//
#include <hip/hip_runtime.h>
#include <hip/hip_bf16.h>

#define B_ 8192
#define C_ 10000
#define D_ 128
#define CPAD 10112      // 158 * 64
#define NPADC 112       // CPAD - C_
#define NT_TOT 158      // 64-col tiles
#define NSTRIP 16
#define STRIPW 10       // strips 0..14 -> 10 tiles, strip 15 -> 8 (even)
#define UPD_BLOCKS 2528 // CPAD/4
#define CVAL_BLOCKS 2048// B_/4

typedef float f32x4 __attribute__((ext_vector_type(4)));
typedef int   i32x8 __attribute__((ext_vector_type(8)));

// ---------------- ws layout (float offsets) ----------------
// counts    : [0, 10240)
// sumx      : [10240, 1290240)
// git_row   : [1290240, 1298432)
// xnorm     : [1298432, 1306624)
// cent_val  : [1306624, 1314816)
// cnorm     : [1314816, 1325056)   (CPAD, pad = 0)
// x_fp4     : byte 5,300,224  (8192 x 64B = 512 KB)
// c_fp4     : byte 7,397,376  (CPAD x 64B = 632 KB, pad rows zero)

// float -> e2m1 code (grid 0,.5,1,1.5,2,3,4,6; RTN)
__device__ inline unsigned fp4q(float v) {
    float m = fabsf(v);
    unsigned s = (__float_as_uint(v) >> 31) << 3;
    unsigned c;
    if      (m < 0.25f) c = 0;
    else if (m < 0.75f) c = 1;
    else if (m < 1.25f) c = 2;
    else if (m < 1.75f) c = 3;
    else if (m < 2.5f)  c = 4;
    else if (m < 3.5f)  c = 5;
    else if (m < 5.0f)  c = 6;
    else                c = 7;
    return s | c;
}

__global__ void zero_ws(float4* __restrict__ ws, float* __restrict__ out) {
    int idx = blockIdx.x * 256 + threadIdx.x;
    if (idx < 324608) ws[idx] = float4{0.f, 0.f, 0.f, 0.f};
    if (idx == 0) { out[0] = 0.f; out[1] = 0.f; }
}

// Fused: segment-sum atomics + fp4 cast + xnorm (single pass over x).
__global__ void scatter_prep(const float* __restrict__ x, const int* __restrict__ labels,
                             float* __restrict__ counts, float* __restrict__ sumx,
                             float* __restrict__ xnorm, unsigned char* __restrict__ xb4) {
    int tid = threadIdx.x;
    int w = tid >> 6, lane = tid & 63;
    int i = blockIdx.x * 4 + w;
    int l = labels[i];
    float2 v = *(const float2*)&x[i * D_ + lane * 2];
    atomicAdd(&sumx[l * D_ + lane * 2], v.x);
    atomicAdd(&sumx[l * D_ + lane * 2 + 1], v.y);
    if (lane == 0) atomicAdd(&counts[l], 1.0f);
    xb4[i * 64 + lane] = (unsigned char)(fp4q(v.x) | (fp4q(v.y) << 4));
    float s = v.x * v.x + v.y * v.y;
    #pragma unroll
    for (int m = 1; m < 64; m <<= 1) s += __shfl_xor(s, m);
    if (lane == 0) xnorm[i] = s;
}

__global__ void upd_cvals(const float* __restrict__ centers, const float* __restrict__ counts,
                          const float* __restrict__ sumx, float* __restrict__ cnorm,
                          unsigned char* __restrict__ cb4, const float* __restrict__ lr,
                          const float* __restrict__ x, const int* __restrict__ labels,
                          float* __restrict__ cent_val) {
    int tid = threadIdx.x;
    int w = tid >> 6, lane = tid & 63;
    int bid = blockIdx.x;
    float lrv = lr[0];

    if (bid < UPD_BLOCKS) {
        int c = bid * 4 + w;
        if (c >= C_) {
            cb4[c * 64 + lane] = 0;
            if (lane == 0) cnorm[c] = 0.0f;
            return;
        }
        float cnt = counts[c];
        float2 cv = *(const float2*)&centers[c * D_ + lane * 2];
        float2 sx = *(const float2*)&sumx[c * D_ + lane * 2];
        float inv = 1.0f / (1.0f + cnt);
        float nx = cv.x - lrv * (cnt * cv.x - sx.x) * inv;
        float ny = cv.y - lrv * (cnt * cv.y - sx.y) * inv;
        cb4[c * 64 + lane] = (unsigned char)(fp4q(nx) | (fp4q(ny) << 4));
        float s = nx * nx + ny * ny;
        #pragma unroll
        for (int m = 1; m < 64; m <<= 1) s += __shfl_xor(s, m);
        if (lane == 0) cnorm[c] = s;
    } else {
        int i = (bid - UPD_BLOCKS) * 4 + w;
        int l = labels[i];
        float cnt = counts[l];
        float inv = 1.0f / (1.0f + cnt);
        float2 a  = *(const float2*)&x[i * D_ + lane * 2];
        float2 cv = *(const float2*)&centers[l * D_ + lane * 2];
        float2 sx = *(const float2*)&sumx[l * D_ + lane * 2];
        float nx = cv.x - lrv * (cnt * cv.x - sx.x) * inv;
        float ny = cv.y - lrv * (cnt * cv.y - sx.y) * inv;
        float dx = a.x - nx, dy = a.y - ny;
        float s = dx * dx + dy * dy;
        #pragma unroll
        for (int m = 1; m < 64; m <<= 1) s += __shfl_xor(s, m);
        if (lane == 0) cent_val[i] = s;
    }
}

// Barrier-free MX-FP4 GEMM + git: NO LDS, NO syncthreads. Each wave marches
// its strip independently; B fragments double-buffered in NAMED register
// sets (fits under explicit (256,2) reg budget: ~210 live). B tile = 4KB,
// L1-resident across the block's 8 waves.
__global__ void __launch_bounds__(256, 2)
gemm_git(const unsigned char* __restrict__ xb4, const unsigned char* __restrict__ cb4,
         const float* __restrict__ xnorm, const float* __restrict__ cnorm,
         float* __restrict__ git_row) {
    int tid = threadIdx.x;
    int w = tid >> 6, lane = tid & 63;
    int lr_ = lane & 15, lg = lane >> 4;
    int bm = blockIdx.x;              // 0..31
    int strip = blockIdx.y;           // 0..15
    int row0 = bm * 256 + w * 64;
    int bn0 = strip * STRIPW;
    int nt = (strip == NSTRIP - 1) ? (NT_TOT - bn0) : STRIPW;

    // A fragments: lane holds row (row0+f*16+lr_), 16B at offset lg*16; pinned.
    i32x8 af[4];
    #pragma unroll
    for (int f = 0; f < 4; f++) {
        const uint4* pa = (const uint4*)(xb4 + (size_t)(row0 + f * 16 + lr_) * 64 + lg * 16);
        uint4 u0 = pa[0];
        asm volatile("" : "+v"(u0.x), "+v"(u0.y), "+v"(u0.z), "+v"(u0.w));
        af[f] = i32x8{(int)u0.x, (int)u0.y, (int)u0.z, (int)u0.w, 0, 0, 0, 0};
    }

    float xn1[4][4];
    #pragma unroll
    for (int fm = 0; fm < 4; fm++)
        #pragma unroll
        for (int r = 0; r < 4; r++) {
            float v = 1.0f + xnorm[row0 + fm * 16 + lg * 4 + r];
            asm volatile("" : "+v"(v));
            xn1[fm][r] = v;
        }

    float gitsum[4][4] = {};

    i32x8 b0[4], b1[4];
    float c0[4], c1[4];

    // load B fragments + cnorm for tile t (16B per fn, per-lane gather)
    auto loadB = [&](int t, i32x8 bf[4], float cn[4]) {
        int cb0 = (bn0 + t) * 64;
        #pragma unroll
        for (int fn = 0; fn < 4; fn++) {
            const uint4* pb = (const uint4*)(cb4 + (size_t)(cb0 + fn * 16 + lr_) * 64 + lg * 16);
            uint4 q = pb[0];
            bf[fn] = i32x8{(int)q.x, (int)q.y, (int)q.z, (int)q.w, 0, 0, 0, 0};
        }
        #pragma unroll
        for (int fn = 0; fn < 4; fn++) cn[fn] = cnorm[(bn0 + t) * 64 + fn * 16 + lr_];
    };

    auto compute = [&](const i32x8 bf[4], const float cn[4]) {
        f32x4 acc[4][4] = {};
        #pragma unroll
        for (int fm = 0; fm < 4; fm++)
            #pragma unroll
            for (int fn = 0; fn < 4; fn++)
                acc[fm][fn] = __builtin_amdgcn_mfma_scale_f32_16x16x128_f8f6f4(
                    af[fm], bf[fn], acc[fm][fn],
                    4, 4,             // cbsz=fp4(e2m1), blgp=fp4(e2m1)
                    0, 0x7F,          // scale_a opsel, scale_a (e8m0 1.0)
                    0, 0x7F);         // scale_b opsel, scale_b
        #pragma unroll
        for (int fm = 0; fm < 4; fm++)
            #pragma unroll
            for (int r = 0; r < 4; r++) {
                float base = xn1[fm][r];
                #pragma unroll
                for (int fp = 0; fp < 4; fp += 2) {
                    float u = base + cn[fp]     - 2.0f * acc[fm][fp][r];
                    float v = base + cn[fp + 1] - 2.0f * acc[fm][fp + 1][r];
                    gitsum[fm][r] += (u + v) * __builtin_amdgcn_rcpf(u * v);
                }
            }
    };

    loadB(0, b0, c0);
    for (int t = 0; t < nt; t += 2) {       // nt is even (10 or 8)
        if (t + 1 < nt) loadB(t + 1, b1, c1);
        compute(b0, c0);
        if (t + 2 < nt) loadB(t + 2, b0, c0);
        compute(b1, c1);
    }

    #pragma unroll
    for (int fm = 0; fm < 4; fm++)
        #pragma unroll
        for (int r = 0; r < 4; r++) {
            float s = gitsum[fm][r];
            s += __shfl_xor(s, 1); s += __shfl_xor(s, 2);
            s += __shfl_xor(s, 4); s += __shfl_xor(s, 8);
            if (lr_ == 0) atomicAdd(&git_row[row0 + fm * 16 + lg * 4 + r], s);
        }
}

__global__ void final_reduce(const float* __restrict__ cent_val, const float* __restrict__ git_row,
                             const float* __restrict__ xnorm, float* __restrict__ out) {
    int tid = threadIdx.x;
    int i = blockIdx.x * 256 + tid;
    float c = cent_val[i];
    float cl = fminf(fmaxf(c, 1e-12f), 1e12f);
    float g = git_row[i] - 1.0f / (1.0f + c) - (float)NPADC / (1.0f + xnorm[i]);
    float gl = fminf(fmaxf(g, 1e-12f), 1e12f);
    #pragma unroll
    for (int m = 1; m < 64; m <<= 1) { cl += __shfl_xor(cl, m); gl += __shfl_xor(gl, m); }
    __shared__ float scl[4], sgl[4];
    if ((tid & 63) == 0) { scl[tid >> 6] = cl; sgl[tid >> 6] = gl; }
    __syncthreads();
    if (tid == 0) {
        float a = scl[0] + scl[1] + scl[2] + scl[3];
        float b = sgl[0] + sgl[1] + sgl[2] + sgl[3];
        atomicAdd(&out[0], a / (float)B_);
        atomicAdd(&out[1], b / (float)B_);
    }
}

extern "C" void kernel_launch(void* const* d_in, const int* in_sizes, int n_in,
                              void* d_out, int out_size, void* d_ws, size_t ws_size,
                              hipStream_t stream) {
    const float* x       = (const float*)d_in[0];
    const int*   labels  = (const int*)d_in[1];
    const float* centers = (const float*)d_in[2];
    const float* lr      = (const float*)d_in[3];

    float* ws       = (float*)d_ws;
    float* counts   = ws;
    float* sumx     = ws + 10240;
    float* git_row  = ws + 1290240;
    float* xnorm    = ws + 1298432;
    float* cent_val = ws + 1306624;
    float* cnorm    = ws + 1314816;
    unsigned char* xb4 = (unsigned char*)d_ws + 5300224;
    unsigned char* cb4 = (unsigned char*)d_ws + 7397376;
    float* out = (float*)d_out;

    zero_ws<<<1268, 256, 0, stream>>>((float4*)d_ws, out);
    scatter_prep<<<B_ / 4, 256, 0, stream>>>(x, labels, counts, sumx, xnorm, xb4);
    upd_cvals<<<UPD_BLOCKS + CVAL_BLOCKS, 256, 0, stream>>>(centers, counts, sumx, cnorm, cb4, lr,
                                                            x, labels, cent_val);
    gemm_git<<<dim3(32, NSTRIP), 256, 0, stream>>>(xb4, cb4, xnorm, cnorm, git_row);
    final_reduce<<<32, 256, 0, stream>>>(cent_val, git_row, xnorm, out);
}